// Round 1
// baseline (477.300 us; speedup 1.0000x reference)
//
#include <hip/hip_runtime.h>
#include <math.h>

namespace {

constexpr int NROWS = 2048;   // B*T
constexpr int DIN   = 512;
constexpr int DOUT  = 512;
constexpr int HEADS = 4;
constexpr int KDIM  = 512;
constexpr int HALFD = 256;
constexpr int NKEYS = 512;
constexpr int KNN   = 32;

// ---------------- order-preserving float<->uint map (for packed argmax) ----
__device__ inline unsigned fmap(float f) {
    unsigned u = __float_as_uint(f);
    return (u & 0x80000000u) ? ~u : (u | 0x80000000u);
}
__device__ inline float funmap(unsigned m) {
    unsigned u = (m & 0x80000000u) ? (m & 0x7FFFFFFFu) : ~m;
    return __uint_as_float(u);
}
__device__ inline unsigned long long shflxor64(unsigned long long x, int m) {
    unsigned lo = (unsigned)x, hi = (unsigned)(x >> 32);
    lo = __shfl_xor(lo, m);
    hi = __shfl_xor(hi, m);
    return ((unsigned long long)hi << 32) | lo;
}

// ---------------- generic f32 NT GEMM: C[m,n] = sum_k A[m,k]*B[n,k] (+bias)
// EPI 0: store acc+bias (bias may be null).  EPI 1: store silu(acc+bias).
// Tile 64x64, BK=16, 256 threads, 4x4 microtile. A/B staged transposed in
// LDS ([BK][64], stride 68 pad) so fragment reads are ds_read_b128.
template<int EPI>
__global__ __launch_bounds__(256)
void gemm_nt(const float* __restrict__ A, int lda,
             const float* __restrict__ B, int ldb,
             float* __restrict__ C, int ldc,
             const float* __restrict__ bias, int K)
{
    __shared__ __align__(16) float as[16][68];
    __shared__ __align__(16) float bs[16][68];
    const int tid = threadIdx.x;
    const int tx = tid & 15, ty = tid >> 4;
    const int m0 = blockIdx.y * 64, n0 = blockIdx.x * 64;
    const int lrow = tid >> 2;          // 0..63
    const int lk4  = (tid & 3) << 2;    // 0,4,8,12
    const float* Ap = A + (size_t)(m0 + lrow) * lda + lk4;
    const float* Bp = B + (size_t)(n0 + lrow) * ldb + lk4;
    float acc[4][4] = {};

    for (int k0 = 0; k0 < K; k0 += 16) {
        const float4 av = *(const float4*)(Ap + k0);
        const float4 bv = *(const float4*)(Bp + k0);
        __syncthreads();
        as[lk4 + 0][lrow] = av.x; as[lk4 + 1][lrow] = av.y;
        as[lk4 + 2][lrow] = av.z; as[lk4 + 3][lrow] = av.w;
        bs[lk4 + 0][lrow] = bv.x; bs[lk4 + 1][lrow] = bv.y;
        bs[lk4 + 2][lrow] = bv.z; bs[lk4 + 3][lrow] = bv.w;
        __syncthreads();
        #pragma unroll
        for (int kk = 0; kk < 16; ++kk) {
            const float4 a = *(const float4*)&as[kk][ty << 2];
            const float4 b = *(const float4*)&bs[kk][tx << 2];
            const float ar[4] = {a.x, a.y, a.z, a.w};
            const float br[4] = {b.x, b.y, b.z, b.w};
            #pragma unroll
            for (int i = 0; i < 4; ++i)
                #pragma unroll
                for (int j = 0; j < 4; ++j)
                    acc[i][j] = fmaf(ar[i], br[j], acc[i][j]);
        }
    }

    float4 bb = {0.f, 0.f, 0.f, 0.f};
    if (bias) bb = *(const float4*)(bias + n0 + (tx << 2));
    #pragma unroll
    for (int i = 0; i < 4; ++i) {
        float4 o;
        o.x = acc[i][0] + bb.x; o.y = acc[i][1] + bb.y;
        o.z = acc[i][2] + bb.z; o.w = acc[i][3] + bb.w;
        if (EPI == 1) {
            o.x = o.x / (1.f + expf(-o.x));
            o.y = o.y / (1.f + expf(-o.y));
            o.z = o.z / (1.f + expf(-o.z));
            o.w = o.w / (1.f + expf(-o.w));
        }
        *(float4*)(C + (size_t)(m0 + (ty << 2) + i) * ldc + n0 + (tx << 2)) = o;
    }
}

// ---------------- two-stage product-key top-k + softmax ---------------------
// One 64-lane block per (n,h).  s layout: s[n][h][half][k], n-stride 4096.
// Stage 1: top-32 of each 512-elem half via 32x iterative wave-argmax on
// packed u64 (value order-bits high, ~index low -> value desc, index asc).
// Stage 2: top-32 of the 32x32 cartesian sums, then softmax.
__global__ __launch_bounds__(64)
void topk_kernel(const float* __restrict__ s,
                 float* __restrict__ w_out, int* __restrict__ idx_out)
{
    const int nh = blockIdx.x;           // n*HEADS + h
    const int lane = threadIdx.x;
    __shared__ float ts[2][KNN];
    __shared__ int   ti[2][KNN];
    const float* sb = s + (size_t)nh * (2 * NKEYS);

    for (int p = 0; p < 2; ++p) {
        float v[8];
        unsigned long long pk[8];
        #pragma unroll
        for (int i = 0; i < 8; ++i) {
            const int e = i * 64 + lane;
            v[i] = sb[p * NKEYS + e];
            pk[i] = ((unsigned long long)fmap(v[i]) << 32) | (unsigned)(~e);
        }
        unsigned usedm = 0;
        for (int it = 0; it < KNN; ++it) {
            unsigned long long best = 0ull;
            #pragma unroll
            for (int i = 0; i < 8; ++i)
                if (!((usedm >> i) & 1u) && pk[i] > best) best = pk[i];
            #pragma unroll
            for (int off = 32; off; off >>= 1) {
                const unsigned long long o = shflxor64(best, off);
                if (o > best) best = o;
            }
            const int e = (int)(~(unsigned)best) & (NKEYS - 1);
            if (lane == 0) {
                ts[p][it] = funmap((unsigned)(best >> 32));
                ti[p][it] = e;
            }
            if ((e & 63) == lane) usedm |= 1u << (e >> 6);
        }
    }
    __syncthreads();

    // cartesian 32x32 = 1024 combos, 16 per lane
    unsigned long long pk2[16];
    #pragma unroll
    for (int t = 0; t < 16; ++t) {
        const int combo = t * 64 + lane;
        const float val = ts[0][combo >> 5] + ts[1][combo & 31];
        pk2[t] = ((unsigned long long)fmap(val) << 32) | (unsigned)(~combo);
    }
    unsigned used2 = 0;
    float mval = 0.f, myval = 0.f;
    int mycombo = 0;
    for (int it = 0; it < KNN; ++it) {
        unsigned long long best = 0ull;
        #pragma unroll
        for (int t = 0; t < 16; ++t)
            if (!((used2 >> t) & 1u) && pk2[t] > best) best = pk2[t];
        #pragma unroll
        for (int off = 32; off; off >>= 1) {
            const unsigned long long o = shflxor64(best, off);
            if (o > best) best = o;
        }
        const int combo = (int)(~(unsigned)best) & 1023;
        const float val = funmap((unsigned)(best >> 32));
        if (it == 0) mval = val;
        if (lane == it) { myval = val; mycombo = combo; }
        if ((combo & 63) == lane) used2 |= 1u << (combo >> 6);
    }

    float e = (lane < KNN) ? expf(myval - mval) : 0.f;
    float ssum = e;
    #pragma unroll
    for (int off = 32; off; off >>= 1) ssum += __shfl_xor(ssum, off);
    if (lane < KNN) {
        const int i1 = ti[0][mycombo >> 5];
        const int i2 = ti[1][mycombo & 31];
        w_out[(size_t)nh * KNN + lane] = e / ssum;
        idx_out[(size_t)nh * KNN + lane] = i1 * NKEYS + i2;
    }
}

// ---------------- weighted embedding-bag gather + gate ---------------------
// One 256-thread block per row n; thread t owns columns 2t, 2t+1.
__global__ __launch_bounds__(256)
void gather_kernel(const float* __restrict__ values,
                   const float* __restrict__ w, const int* __restrict__ idx,
                   const float* __restrict__ gate, float* __restrict__ out0)
{
    const int n = blockIdx.x;
    const int t = threadIdx.x;
    __shared__ float sw[HEADS * KNN];
    __shared__ int   sidx[HEADS * KNN];
    if (t < HEADS * KNN) {
        sw[t]   = w[(size_t)n * HEADS * KNN + t];
        sidx[t] = idx[(size_t)n * HEADS * KNN + t];
    }
    __syncthreads();
    const int d0 = t * 2;
    float2 acc = {0.f, 0.f};
    #pragma unroll 4
    for (int k = 0; k < HEADS * KNN; ++k) {
        const float2 v = *(const float2*)(values + (size_t)sidx[k] * DOUT + d0);
        const float ww = sw[k];
        acc.x = fmaf(ww, v.x, acc.x);
        acc.y = fmaf(ww, v.y, acc.y);
    }
    const float2 g = *(const float2*)(gate + (size_t)n * DOUT + d0);
    acc.x *= g.x;
    acc.y *= g.y;
    *(float2*)(out0 + (size_t)n * DOUT + d0) = acc;
}

}  // namespace

extern "C" void kernel_launch(void* const* d_in, const int* in_sizes, int n_in,
                              void* d_out, int out_size, void* d_ws, size_t ws_size,
                              hipStream_t stream)
{
    const float* x      = (const float*)d_in[0];
    const float* Wq     = (const float*)d_in[1];
    const float* bq     = (const float*)d_in[2];
    const float* keys   = (const float*)d_in[3];
    const float* values = (const float*)d_in[4];
    const float* Wsw    = (const float*)d_in[5];
    const float* bsw    = (const float*)d_in[6];
    const float* Wv     = (const float*)d_in[7];
    const float* bv     = (const float*)d_in[8];
    float* out = (float*)d_out;

    // workspace layout (peak ~50 MB):
    //   region0 [16 MB]: q (2048x2048); reused after topk for gate + out0
    //   region1 [32 MB]: s (2048x4096)
    //   region2 [ 2 MB]: softmax weights (2048x128 f32) + indices (2048x128 i32)
    float* q    = (float*)d_ws;
    float* s    = q + (size_t)NROWS * HEADS * KDIM;
    float* wsc  = s + (size_t)NROWS * HEADS * 2 * NKEYS;
    int*   idxb = (int*)(wsc + (size_t)NROWS * HEADS * KNN);
    float* gate = q;                                  // q dead after topk
    float* out0 = gate + (size_t)NROWS * DOUT;

    const dim3 blk(256);

    // 1) q = x @ Wq^T + bq           (2048 x 2048, K=512)
    gemm_nt<0><<<dim3(32, 32), blk, 0, stream>>>(
        x, DIN, Wq, DIN, q, HEADS * KDIM, bq, DIN);

    // 2) scores: per (head, half)    (2048 x 512, K=256), 8 launches
    for (int h = 0; h < HEADS; ++h)
        for (int p = 0; p < 2; ++p)
            gemm_nt<0><<<dim3(8, 32), blk, 0, stream>>>(
                q + h * KDIM + p * HALFD, HEADS * KDIM,
                keys + (size_t)(h * 2 + p) * NKEYS * HALFD, HALFD,
                s + (h * 2 + p) * NKEYS, HEADS * 2 * NKEYS,
                nullptr, HALFD);

    // 3) two-stage top-32 + softmax  (one wave per (n,h))
    topk_kernel<<<dim3(NROWS * HEADS), dim3(64), 0, stream>>>(s, wsc, idxb);

    // 4) gate = silu(x @ Wsw^T + bsw)
    gemm_nt<1><<<dim3(8, 32), blk, 0, stream>>>(
        x, DIN, Wsw, DIN, gate, DOUT, bsw, DIN);

    // 5) out0 = (sum_k w*values[idx]) * gate
    gather_kernel<<<dim3(NROWS), blk, 0, stream>>>(values, wsc, idxb, gate, out0);

    // 6) out = out0 @ Wv^T + bv
    gemm_nt<0><<<dim3(8, 32), blk, 0, stream>>>(
        out0, DOUT, Wv, DOUT, out, DOUT, bv, DOUT);
}

// Round 2
// 354.906 us; speedup vs baseline: 1.3449x; 1.3449x over previous
//
#include <hip/hip_runtime.h>
#include <math.h>

namespace {

constexpr int NROWS = 2048;   // B*T
constexpr int DIN   = 512;
constexpr int DOUT  = 512;
constexpr int HEADS = 4;
constexpr int KDIM  = 512;
constexpr int HALFD = 256;
constexpr int NKEYS = 512;
constexpr int KNN   = 32;

// =================== big-tile f32 NT GEMM body: 128x64, 8x4 micro ==========
// C[m,n] = sum_k A[m,k]*B[n,k] (+bias).  K % 16 == 0, M % 128 == 0, N % 64 == 0.
__device__ inline void gemm128x64_body(const float* __restrict__ A, int lda,
                                       const float* __restrict__ B, int ldb,
                                       float* __restrict__ C, int ldc,
                                       const float* __restrict__ bias, int K,
                                       int m0, int n0)
{
    __shared__ __align__(16) float as[16][132];
    __shared__ __align__(16) float bs[16][68];
    const int tid = threadIdx.x;
    const int tx = tid & 15;          // n: 4 cols each
    const int ty = tid >> 4;          // m: 8 rows each
    const int lrA = tid >> 1, lkA = (tid & 1) << 3;
    const int lrB = tid >> 2, lkB = (tid & 3) << 2;
    const float* Ap = A + (size_t)(m0 + lrA) * lda + lkA;
    const float* Bp = B + (size_t)(n0 + lrB) * ldb + lkB;
    float acc[8][4] = {};

    for (int k0 = 0; k0 < K; k0 += 16) {
        const float4 a0 = *(const float4*)(Ap + k0);
        const float4 a1 = *(const float4*)(Ap + k0 + 4);
        const float4 b0 = *(const float4*)(Bp + k0);
        __syncthreads();
        as[lkA + 0][lrA] = a0.x; as[lkA + 1][lrA] = a0.y;
        as[lkA + 2][lrA] = a0.z; as[lkA + 3][lrA] = a0.w;
        as[lkA + 4][lrA] = a1.x; as[lkA + 5][lrA] = a1.y;
        as[lkA + 6][lrA] = a1.z; as[lkA + 7][lrA] = a1.w;
        bs[lkB + 0][lrB] = b0.x; bs[lkB + 1][lrB] = b0.y;
        bs[lkB + 2][lrB] = b0.z; bs[lkB + 3][lrB] = b0.w;
        __syncthreads();
        #pragma unroll
        for (int kk = 0; kk < 16; ++kk) {
            const float4 a0v = *(const float4*)&as[kk][ty << 3];
            const float4 a1v = *(const float4*)&as[kk][(ty << 3) + 4];
            const float4 bv  = *(const float4*)&bs[kk][tx << 2];
            const float ar[8] = {a0v.x, a0v.y, a0v.z, a0v.w,
                                 a1v.x, a1v.y, a1v.z, a1v.w};
            const float br[4] = {bv.x, bv.y, bv.z, bv.w};
            #pragma unroll
            for (int i = 0; i < 8; ++i)
                #pragma unroll
                for (int j = 0; j < 4; ++j)
                    acc[i][j] = fmaf(ar[i], br[j], acc[i][j]);
        }
    }

    float4 bb = {0.f, 0.f, 0.f, 0.f};
    if (bias) bb = *(const float4*)(bias + n0 + (tx << 2));
    #pragma unroll
    for (int i = 0; i < 8; ++i) {
        float4 o;
        o.x = acc[i][0] + bb.x; o.y = acc[i][1] + bb.y;
        o.z = acc[i][2] + bb.z; o.w = acc[i][3] + bb.w;
        *(float4*)(C + (size_t)(m0 + (ty << 3) + i) * ldc + n0 + (tx << 2)) = o;
    }
}

__global__ __launch_bounds__(256)
void gemm_big(const float* __restrict__ A, int lda,
              const float* __restrict__ B, int ldb,
              float* __restrict__ C, int ldc,
              const float* __restrict__ bias, int K)
{
    gemm128x64_body(A, lda, B, ldb, C, ldc, bias, K,
                    blockIdx.y * 128, blockIdx.x * 64);
}

// all 8 (head, half) score GEMMs in one launch via blockIdx.z
__global__ __launch_bounds__(256)
void score_gemm(const float* __restrict__ q, const float* __restrict__ keys,
                float* __restrict__ s)
{
    const int z = blockIdx.z;            // h*2 + p
    gemm128x64_body(q + (z >> 1) * KDIM + (z & 1) * HALFD, HEADS * KDIM,
                    keys + (size_t)z * NKEYS * HALFD, HALFD,
                    s + z * NKEYS, HEADS * 2 * NKEYS, nullptr, HALFD,
                    blockIdx.y * 128, blockIdx.x * 64);
}

// =================== small-tile f32 NT GEMM: 64x64, 4x4 micro ==============
// EPI 0: acc+bias.  EPI 1: silu(acc+bias).
template<int EPI>
__global__ __launch_bounds__(256)
void gemm_nt(const float* __restrict__ A, int lda,
             const float* __restrict__ B, int ldb,
             float* __restrict__ C, int ldc,
             const float* __restrict__ bias, int K)
{
    __shared__ __align__(16) float as[16][68];
    __shared__ __align__(16) float bs[16][68];
    const int tid = threadIdx.x;
    const int tx = tid & 15, ty = tid >> 4;
    const int m0 = blockIdx.y * 64, n0 = blockIdx.x * 64;
    const int lrow = tid >> 2;
    const int lk4  = (tid & 3) << 2;
    const float* Ap = A + (size_t)(m0 + lrow) * lda + lk4;
    const float* Bp = B + (size_t)(n0 + lrow) * ldb + lk4;
    float acc[4][4] = {};

    for (int k0 = 0; k0 < K; k0 += 16) {
        const float4 av = *(const float4*)(Ap + k0);
        const float4 bv = *(const float4*)(Bp + k0);
        __syncthreads();
        as[lk4 + 0][lrow] = av.x; as[lk4 + 1][lrow] = av.y;
        as[lk4 + 2][lrow] = av.z; as[lk4 + 3][lrow] = av.w;
        bs[lk4 + 0][lrow] = bv.x; bs[lk4 + 1][lrow] = bv.y;
        bs[lk4 + 2][lrow] = bv.z; bs[lk4 + 3][lrow] = bv.w;
        __syncthreads();
        #pragma unroll
        for (int kk = 0; kk < 16; ++kk) {
            const float4 a = *(const float4*)&as[kk][ty << 2];
            const float4 b = *(const float4*)&bs[kk][tx << 2];
            const float ar[4] = {a.x, a.y, a.z, a.w};
            const float br[4] = {b.x, b.y, b.z, b.w};
            #pragma unroll
            for (int i = 0; i < 4; ++i)
                #pragma unroll
                for (int j = 0; j < 4; ++j)
                    acc[i][j] = fmaf(ar[i], br[j], acc[i][j]);
        }
    }

    float4 bb = {0.f, 0.f, 0.f, 0.f};
    if (bias) bb = *(const float4*)(bias + n0 + (tx << 2));
    #pragma unroll
    for (int i = 0; i < 4; ++i) {
        float4 o;
        o.x = acc[i][0] + bb.x; o.y = acc[i][1] + bb.y;
        o.z = acc[i][2] + bb.z; o.w = acc[i][3] + bb.w;
        if (EPI == 1) {
            o.x = o.x / (1.f + expf(-o.x));
            o.y = o.y / (1.f + expf(-o.y));
            o.z = o.z / (1.f + expf(-o.z));
            o.w = o.w / (1.f + expf(-o.w));
        }
        *(float4*)(C + (size_t)(m0 + (ty << 2) + i) * ldc + n0 + (tx << 2)) = o;
    }
}

// =================== two-stage product-key top-k + softmax =================
// One 64-lane wave per (n,h).  Stage 1 runs BOTH halves concurrently on
// 32-lane subgroups (16 elems/lane).  Stage 2 prunes the 32x32 cartesian
// sums to the 119 candidates with (i+1)*(j+1) <= 32 (provably a superset of
// the top-32 under value-desc/index-asc ordering), then 32 argmax rounds.
// Ties resolved exactly: value desc, element index asc (matches lax.top_k).
__global__ __launch_bounds__(64)
void topk_kernel(const float* __restrict__ s,
                 float* __restrict__ w_out, int* __restrict__ idx_out)
{
    const int nh   = blockIdx.x;
    const int lane = threadIdx.x;
    const int sub  = lane >> 5;          // which half (0/1)
    const int sl   = lane & 31;
    __shared__ float ts[2][KNN];
    __shared__ int   ti[2][KNN];
    const float* sb = s + (size_t)nh * (2 * NKEYS) + sub * NKEYS;

    // ---- stage 1: per-half top-32 of 512 ----
    float v[16];
    #pragma unroll
    for (int i = 0; i < 16; ++i) v[i] = sb[i * 32 + sl];
    unsigned used = 0;
    for (int it = 0; it < KNN; ++it) {
        float bv = -INFINITY; int bi = 0;
        #pragma unroll
        for (int i = 0; i < 16; ++i) {
            const bool ok = !((used >> i) & 1u) && v[i] > bv;
            bv = ok ? v[i] : bv;
            bi = ok ? i : bi;
        }
        float m = bv;
        #pragma unroll
        for (int off = 16; off; off >>= 1) m = fmaxf(m, __shfl_xor(m, off));
        const int cand = (bv == m) ? ((bi << 5) | sl) : 0x7fffffff;
        const unsigned long long bal = __ballot(bv == m);
        const unsigned half = (unsigned)(bal >> (sub << 5));
        int e;
        if (__popc(half) == 1) {                       // common case
            e = __shfl(cand, (sub << 5) + (__ffs(half) - 1));
        } else {                                       // exact tie fallback
            int cm = cand;
            #pragma unroll
            for (int off = 16; off; off >>= 1) cm = min(cm, __shfl_xor(cm, off));
            e = cm;
        }
        if (sl == 0) { ts[sub][it] = m; ti[sub][it] = e; }
        if (sl == (e & 31)) used |= 1u << (e >> 5);
    }
    __syncthreads();

    // ---- stage 2: top-32 of pruned cartesian sums ----
    float cv[2]; int cc[2];
    #pragma unroll
    for (int t = 0; t < 2; ++t) {
        const int c = t * 64 + lane;
        int ii = -1, jj = 0, off = 0;
        #pragma unroll
        for (int i = 0; i < 32; ++i) {
            const int cnt = 32 / (i + 1);
            const bool in = (c >= off) && (c < off + cnt);
            ii = in ? i : ii;
            jj = in ? c - off : jj;
            off += cnt;
        }
        if (ii >= 0) { cv[t] = ts[0][ii] + ts[1][jj]; cc[t] = ii * 32 + jj; }
        else         { cv[t] = -INFINITY;             cc[t] = 0x7fffffff;  }
    }

    unsigned used2 = 0;
    float mval = 0.f, myval = -INFINITY;
    int mycombo = 0;
    for (int it = 0; it < KNN; ++it) {
        float bv = -INFINITY; int bc = 0x7fffffff;
        #pragma unroll
        for (int t = 0; t < 2; ++t) {
            const bool live = !((used2 >> t) & 1u);
            const bool better = live &&
                (cv[t] > bv || (cv[t] == bv && cc[t] < bc));
            bv = better ? cv[t] : bv;
            bc = better ? cc[t] : bc;
        }
        float m = bv;
        #pragma unroll
        for (int off = 32; off; off >>= 1) m = fmaxf(m, __shfl_xor(m, off));
        const unsigned long long bal = __ballot(bv == m);
        int combo;
        if (__popcll(bal) == 1) {
            combo = __shfl(bc, (int)(__ffsll(bal) - 1));
        } else {
            unsigned cm = (bv == m) ? (unsigned)bc : 0xffffffffu;
            #pragma unroll
            for (int off = 32; off; off >>= 1) cm = min(cm, __shfl_xor(cm, off));
            combo = (int)cm;
        }
        if (it == 0) mval = m;
        if (lane == it) { myval = m; mycombo = combo; }
        #pragma unroll
        for (int t = 0; t < 2; ++t)
            if (cc[t] == combo) used2 |= 1u << t;
    }

    const float ew = (lane < KNN) ? expf(myval - mval) : 0.f;
    float ssum = ew;
    #pragma unroll
    for (int off = 32; off; off >>= 1) ssum += __shfl_xor(ssum, off);
    if (lane < KNN) {
        const int i1 = ti[0][mycombo >> 5];
        const int i2 = ti[1][mycombo & 31];
        w_out[(size_t)nh * KNN + lane] = ew / ssum;
        idx_out[(size_t)nh * KNN + lane] = i1 * NKEYS + i2;
    }
}

// =================== weighted embedding-bag gather + gate ==================
__global__ __launch_bounds__(256)
void gather_kernel(const float* __restrict__ values,
                   const float* __restrict__ w, const int* __restrict__ idx,
                   const float* __restrict__ gate, float* __restrict__ out0)
{
    const int n = blockIdx.x;
    const int t = threadIdx.x;
    __shared__ float sw[HEADS * KNN];
    __shared__ int   sidx[HEADS * KNN];
    if (t < HEADS * KNN) {
        sw[t]   = w[(size_t)n * HEADS * KNN + t];
        sidx[t] = idx[(size_t)n * HEADS * KNN + t];
    }
    __syncthreads();
    const int d0 = t * 2;
    float2 acc = {0.f, 0.f};
    #pragma unroll 8
    for (int k = 0; k < HEADS * KNN; ++k) {
        const float2 v = *(const float2*)(values + (size_t)sidx[k] * DOUT + d0);
        const float ww = sw[k];
        acc.x = fmaf(ww, v.x, acc.x);
        acc.y = fmaf(ww, v.y, acc.y);
    }
    const float2 g = *(const float2*)(gate + (size_t)n * DOUT + d0);
    acc.x *= g.x;
    acc.y *= g.y;
    *(float2*)(out0 + (size_t)n * DOUT + d0) = acc;
}

}  // namespace

extern "C" void kernel_launch(void* const* d_in, const int* in_sizes, int n_in,
                              void* d_out, int out_size, void* d_ws, size_t ws_size,
                              hipStream_t stream)
{
    const float* x      = (const float*)d_in[0];
    const float* Wq     = (const float*)d_in[1];
    const float* bq     = (const float*)d_in[2];
    const float* keys   = (const float*)d_in[3];
    const float* values = (const float*)d_in[4];
    const float* Wsw    = (const float*)d_in[5];
    const float* bsw    = (const float*)d_in[6];
    const float* Wv     = (const float*)d_in[7];
    const float* bv     = (const float*)d_in[8];
    float* out = (float*)d_out;

    // workspace: q (16MB) | s (32MB) | weights+indices (2MB); gate/out0 reuse q
    float* q    = (float*)d_ws;
    float* s    = q + (size_t)NROWS * HEADS * KDIM;
    float* wsc  = s + (size_t)NROWS * HEADS * 2 * NKEYS;
    int*   idxb = (int*)(wsc + (size_t)NROWS * HEADS * KNN);
    float* gate = q;                                  // q dead after topk
    float* out0 = gate + (size_t)NROWS * DOUT;

    const dim3 blk(256);

    // 1) q = x @ Wq^T + bq            (2048 x 2048, K=512)
    gemm_big<<<dim3(32, 16), blk, 0, stream>>>(
        x, DIN, Wq, DIN, q, HEADS * KDIM, bq, DIN);

    // 2) scores, all 8 (h,p) fused    (2048 x 512, K=256 each)
    score_gemm<<<dim3(8, 16, 8), blk, 0, stream>>>(q, keys, s);

    // 3) two-stage top-32 + softmax
    topk_kernel<<<dim3(NROWS * HEADS), dim3(64), 0, stream>>>(s, wsc, idxb);

    // 4) gate = silu(x @ Wsw^T + bsw)
    gemm_nt<1><<<dim3(8, 32), blk, 0, stream>>>(
        x, DIN, Wsw, DIN, gate, DOUT, bsw, DIN);

    // 5) out0 = (sum_k w*values[idx]) * gate
    gather_kernel<<<dim3(NROWS), blk, 0, stream>>>(values, wsc, idxb, gate, out0);

    // 6) out = out0 @ Wv^T + bv
    gemm_nt<0><<<dim3(8, 32), blk, 0, stream>>>(
        out0, DOUT, Wv, DOUT, out, DOUT, bv, DOUT);
}

// Round 4
// 338.903 us; speedup vs baseline: 1.4084x; 1.0472x over previous
//
#include <hip/hip_runtime.h>
#include <math.h>

namespace {

constexpr int NROWS = 2048;   // B*T
constexpr int DIN   = 512;
constexpr int DOUT  = 512;
constexpr int HEADS = 4;
constexpr int KDIM  = 512;
constexpr int HALFD = 256;
constexpr int NKEYS = 512;
constexpr int KNN   = 32;

// =================== big-tile f32 NT GEMM body: 128x64, 8x4 micro ==========
// C[m,n] = sum_k A[m,k]*B[n,k] (+bias).  EPI 1 = silu epilogue.
// Prefetched: next K-step's global loads issue before the compute phase.
template<int EPI>
__device__ inline void gemm128x64_body(const float* __restrict__ A, int lda,
                                       const float* __restrict__ B, int ldb,
                                       float* __restrict__ C, int ldc,
                                       const float* __restrict__ bias, int K,
                                       int m0, int n0)
{
    __shared__ __align__(16) float as[16][132];
    __shared__ __align__(16) float bs[16][68];
    const int tid = threadIdx.x;
    const int tx = tid & 15;          // n: 4 cols each
    const int ty = tid >> 4;          // m: 8 rows each
    const int lrA = tid >> 1, lkA = (tid & 1) << 3;
    const int lrB = tid >> 2, lkB = (tid & 3) << 2;
    const float* Ap = A + (size_t)(m0 + lrA) * lda + lkA;
    const float* Bp = B + (size_t)(n0 + lrB) * ldb + lkB;
    float acc[8][4] = {};

    float4 a0 = *(const float4*)(Ap);
    float4 a1 = *(const float4*)(Ap + 4);
    float4 b0 = *(const float4*)(Bp);

    for (int k0 = 0; k0 < K; k0 += 16) {
        __syncthreads();                       // prev compute done reading LDS
        as[lkA + 0][lrA] = a0.x; as[lkA + 1][lrA] = a0.y;
        as[lkA + 2][lrA] = a0.z; as[lkA + 3][lrA] = a0.w;
        as[lkA + 4][lrA] = a1.x; as[lkA + 5][lrA] = a1.y;
        as[lkA + 6][lrA] = a1.z; as[lkA + 7][lrA] = a1.w;
        bs[lkB + 0][lrB] = b0.x; bs[lkB + 1][lrB] = b0.y;
        bs[lkB + 2][lrB] = b0.z; bs[lkB + 3][lrB] = b0.w;
        __syncthreads();
        if (k0 + 16 < K) {                     // prefetch next K-step (T14)
            a0 = *(const float4*)(Ap + k0 + 16);
            a1 = *(const float4*)(Ap + k0 + 20);
            b0 = *(const float4*)(Bp + k0 + 16);
        }
        #pragma unroll
        for (int kk = 0; kk < 16; ++kk) {
            const float4 a0v = *(const float4*)&as[kk][ty << 3];
            const float4 a1v = *(const float4*)&as[kk][(ty << 3) + 4];
            const float4 bv  = *(const float4*)&bs[kk][tx << 2];
            const float ar[8] = {a0v.x, a0v.y, a0v.z, a0v.w,
                                 a1v.x, a1v.y, a1v.z, a1v.w};
            const float br[4] = {bv.x, bv.y, bv.z, bv.w};
            #pragma unroll
            for (int i = 0; i < 8; ++i)
                #pragma unroll
                for (int j = 0; j < 4; ++j)
                    acc[i][j] = fmaf(ar[i], br[j], acc[i][j]);
        }
    }

    float4 bb = {0.f, 0.f, 0.f, 0.f};
    if (bias) bb = *(const float4*)(bias + n0 + (tx << 2));
    #pragma unroll
    for (int i = 0; i < 8; ++i) {
        float4 o;
        o.x = acc[i][0] + bb.x; o.y = acc[i][1] + bb.y;
        o.z = acc[i][2] + bb.z; o.w = acc[i][3] + bb.w;
        if (EPI == 1) {
            o.x = o.x / (1.f + expf(-o.x));
            o.y = o.y / (1.f + expf(-o.y));
            o.z = o.z / (1.f + expf(-o.z));
            o.w = o.w / (1.f + expf(-o.w));
        }
        *(float4*)(C + (size_t)(m0 + (ty << 3) + i) * ldc + n0 + (tx << 2)) = o;
    }
}

// q = x @ Wq^T + bq
__global__ __launch_bounds__(256)
void gemm_big(const float* __restrict__ A, int lda,
              const float* __restrict__ B, int ldb,
              float* __restrict__ C, int ldc,
              const float* __restrict__ bias, int K)
{
    gemm128x64_body<0>(A, lda, B, ldb, C, ldc, bias, K,
                       blockIdx.y * 128, blockIdx.x * 64);
}

// z<8: s_z = q_z @ keys_z^T  (K=256)  |  z==8: gate = silu(x@Wsw^T+bsw) (K=512)
__global__ __launch_bounds__(256)
void score_gate_gemm(const float* __restrict__ q, const float* __restrict__ keys,
                     const float* __restrict__ x,
                     const float* __restrict__ Wsw, const float* __restrict__ bsw,
                     float* __restrict__ s, float* __restrict__ gate)
{
    const int z = blockIdx.z;
    if (z < 8)
        gemm128x64_body<0>(q + (z >> 1) * KDIM + (z & 1) * HALFD, HEADS * KDIM,
                           keys + (size_t)z * NKEYS * HALFD, HALFD,
                           s + z * NKEYS, HEADS * 2 * NKEYS, nullptr, HALFD,
                           blockIdx.y * 128, blockIdx.x * 64);
    else
        gemm128x64_body<1>(x, DIN, Wsw, DIN, gate, DOUT, bsw, DIN,
                           blockIdx.y * 128, blockIdx.x * 64);
}

// =================== small-tile f32 NT GEMM: 64x64, 4x4 micro (prefetched) =
__global__ __launch_bounds__(256)
void gemm_nt(const float* __restrict__ A, int lda,
             const float* __restrict__ B, int ldb,
             float* __restrict__ C, int ldc,
             const float* __restrict__ bias, int K)
{
    __shared__ __align__(16) float as[16][68];
    __shared__ __align__(16) float bs[16][68];
    const int tid = threadIdx.x;
    const int tx = tid & 15, ty = tid >> 4;
    const int m0 = blockIdx.y * 64, n0 = blockIdx.x * 64;
    const int lrow = tid >> 2;
    const int lk4  = (tid & 3) << 2;
    const float* Ap = A + (size_t)(m0 + lrow) * lda + lk4;
    const float* Bp = B + (size_t)(n0 + lrow) * ldb + lk4;
    float acc[4][4] = {};

    float4 av = *(const float4*)(Ap);
    float4 bv = *(const float4*)(Bp);
    for (int k0 = 0; k0 < K; k0 += 16) {
        __syncthreads();
        as[lk4 + 0][lrow] = av.x; as[lk4 + 1][lrow] = av.y;
        as[lk4 + 2][lrow] = av.z; as[lk4 + 3][lrow] = av.w;
        bs[lk4 + 0][lrow] = bv.x; bs[lk4 + 1][lrow] = bv.y;
        bs[lk4 + 2][lrow] = bv.z; bs[lk4 + 3][lrow] = bv.w;
        __syncthreads();
        if (k0 + 16 < K) {
            av = *(const float4*)(Ap + k0 + 16);
            bv = *(const float4*)(Bp + k0 + 16);
        }
        #pragma unroll
        for (int kk = 0; kk < 16; ++kk) {
            const float4 a = *(const float4*)&as[kk][ty << 2];
            const float4 b = *(const float4*)&bs[kk][tx << 2];
            const float ar[4] = {a.x, a.y, a.z, a.w};
            const float br[4] = {b.x, b.y, b.z, b.w};
            #pragma unroll
            for (int i = 0; i < 4; ++i)
                #pragma unroll
                for (int j = 0; j < 4; ++j)
                    acc[i][j] = fmaf(ar[i], br[j], acc[i][j]);
        }
    }

    float4 bb = {0.f, 0.f, 0.f, 0.f};
    if (bias) bb = *(const float4*)(bias + n0 + (tx << 2));
    #pragma unroll
    for (int i = 0; i < 4; ++i) {
        float4 o;
        o.x = acc[i][0] + bb.x; o.y = acc[i][1] + bb.y;
        o.z = acc[i][2] + bb.z; o.w = acc[i][3] + bb.w;
        *(float4*)(C + (size_t)(m0 + (ty << 2) + i) * ldc + n0 + (tx << 2)) = o;
    }
}

// =================== two-stage product-key top-k + softmax =================
// (identical to the R2-verified kernel)
__global__ __launch_bounds__(64)
void topk_kernel(const float* __restrict__ s,
                 float* __restrict__ w_out, int* __restrict__ idx_out)
{
    const int nh   = blockIdx.x;
    const int lane = threadIdx.x;
    const int sub  = lane >> 5;
    const int sl   = lane & 31;
    __shared__ float ts[2][KNN];
    __shared__ int   ti[2][KNN];
    const float* sb = s + (size_t)nh * (2 * NKEYS) + sub * NKEYS;

    float v[16];
    #pragma unroll
    for (int i = 0; i < 16; ++i) v[i] = sb[i * 32 + sl];
    unsigned used = 0;
    for (int it = 0; it < KNN; ++it) {
        float bv = -INFINITY; int bi = 0;
        #pragma unroll
        for (int i = 0; i < 16; ++i) {
            const bool ok = !((used >> i) & 1u) && v[i] > bv;
            bv = ok ? v[i] : bv;
            bi = ok ? i : bi;
        }
        float m = bv;
        #pragma unroll
        for (int off = 16; off; off >>= 1) m = fmaxf(m, __shfl_xor(m, off));
        const int cand = (bv == m) ? ((bi << 5) | sl) : 0x7fffffff;
        const unsigned long long bal = __ballot(bv == m);
        const unsigned half = (unsigned)(bal >> (sub << 5));
        int e;
        if (__popc(half) == 1) {
            e = __shfl(cand, (sub << 5) + (__ffs(half) - 1));
        } else {
            int cm = cand;
            #pragma unroll
            for (int off = 16; off; off >>= 1) cm = min(cm, __shfl_xor(cm, off));
            e = cm;
        }
        if (sl == 0) { ts[sub][it] = m; ti[sub][it] = e; }
        if (sl == (e & 31)) used |= 1u << (e >> 5);
    }
    __syncthreads();

    float cv[2]; int cc[2];
    #pragma unroll
    for (int t = 0; t < 2; ++t) {
        const int c = t * 64 + lane;
        int ii = -1, jj = 0, off = 0;
        #pragma unroll
        for (int i = 0; i < 32; ++i) {
            const int cnt = 32 / (i + 1);
            const bool in = (c >= off) && (c < off + cnt);
            ii = in ? i : ii;
            jj = in ? c - off : jj;
            off += cnt;
        }
        if (ii >= 0) { cv[t] = ts[0][ii] + ts[1][jj]; cc[t] = ii * 32 + jj; }
        else         { cv[t] = -INFINITY;             cc[t] = 0x7fffffff;  }
    }

    unsigned used2 = 0;
    float mval = 0.f, myval = -INFINITY;
    int mycombo = 0;
    for (int it = 0; it < KNN; ++it) {
        float bv = -INFINITY; int bc = 0x7fffffff;
        #pragma unroll
        for (int t = 0; t < 2; ++t) {
            const bool live = !((used2 >> t) & 1u);
            const bool better = live &&
                (cv[t] > bv || (cv[t] == bv && cc[t] < bc));
            bv = better ? cv[t] : bv;
            bc = better ? cc[t] : bc;
        }
        float m = bv;
        #pragma unroll
        for (int off = 32; off; off >>= 1) m = fmaxf(m, __shfl_xor(m, off));
        const unsigned long long bal = __ballot(bv == m);
        int combo;
        if (__popcll(bal) == 1) {
            combo = __shfl(bc, (int)(__ffsll(bal) - 1));
        } else {
            unsigned cm = (bv == m) ? (unsigned)bc : 0xffffffffu;
            #pragma unroll
            for (int off = 32; off; off >>= 1) cm = min(cm, __shfl_xor(cm, off));
            combo = (int)cm;
        }
        if (it == 0) mval = m;
        if (lane == it) { myval = m; mycombo = combo; }
        #pragma unroll
        for (int t = 0; t < 2; ++t)
            if (cc[t] == combo) used2 |= 1u << t;
    }

    const float ew = (lane < KNN) ? expf(myval - mval) : 0.f;
    float ssum = ew;
    #pragma unroll
    for (int off = 32; off; off >>= 1) ssum += __shfl_xor(ssum, off);
    if (lane < KNN) {
        const int i1 = ti[0][mycombo >> 5];
        const int i2 = ti[1][mycombo & 31];
        w_out[(size_t)nh * KNN + lane] = ew / ssum;
        idx_out[(size_t)nh * KNN + lane] = i1 * NKEYS + i2;
    }
}

// =================== weighted embedding-bag gather + gate ==================
__global__ __launch_bounds__(256)
void gather_kernel(const float* __restrict__ values,
                   const float* __restrict__ w, const int* __restrict__ idx,
                   const float* __restrict__ gate, float* __restrict__ out0)
{
    const int n = blockIdx.x;
    const int t = threadIdx.x;
    __shared__ float sw[HEADS * KNN];
    __shared__ int   sidx[HEADS * KNN];
    if (t < HEADS * KNN) {
        sw[t]   = w[(size_t)n * HEADS * KNN + t];
        sidx[t] = idx[(size_t)n * HEADS * KNN + t];
    }
    __syncthreads();
    const int d0 = t * 2;
    float2 acc = {0.f, 0.f};
    #pragma unroll 8
    for (int k = 0; k < HEADS * KNN; ++k) {
        const float2 v = *(const float2*)(values + (size_t)sidx[k] * DOUT + d0);
        const float ww = sw[k];
        acc.x = fmaf(ww, v.x, acc.x);
        acc.y = fmaf(ww, v.y, acc.y);
    }
    const float2 g = *(const float2*)(gate + (size_t)n * DOUT + d0);
    acc.x *= g.x;
    acc.y *= g.y;
    *(float2*)(out0 + (size_t)n * DOUT + d0) = acc;
}

}  // namespace

extern "C" void kernel_launch(void* const* d_in, const int* in_sizes, int n_in,
                              void* d_out, int out_size, void* d_ws, size_t ws_size,
                              hipStream_t stream)
{
    const float* x      = (const float*)d_in[0];
    const float* Wq     = (const float*)d_in[1];
    const float* bq     = (const float*)d_in[2];
    const float* keys   = (const float*)d_in[3];
    const float* values = (const float*)d_in[4];
    const float* Wsw    = (const float*)d_in[5];
    const float* bsw    = (const float*)d_in[6];
    const float* Wv     = (const float*)d_in[7];
    const float* bv     = (const float*)d_in[8];
    float* out = (float*)d_out;

    // ws: q 16MB | s 32MB | wsc 1MB | idx 1MB | gate 4MB | out0 4MB
    float* q    = (float*)d_ws;
    float* s    = q + (size_t)NROWS * HEADS * KDIM;
    float* wsc  = s + (size_t)NROWS * HEADS * 2 * NKEYS;
    int*   idxb = (int*)(wsc + (size_t)NROWS * HEADS * KNN);
    float* gate = (float*)(idxb + (size_t)NROWS * HEADS * KNN);
    float* out0 = gate + (size_t)NROWS * DOUT;

    const dim3 blk(256);

    // 1) q = x @ Wq^T + bq            (2048 x 2048, K=512)
    gemm_big<<<dim3(32, 16), blk, 0, stream>>>(
        x, DIN, Wq, DIN, q, HEADS * KDIM, bq, DIN);

    // 2) scores (z<8, K=256) + gate (z==8, K=512) in one launch
    score_gate_gemm<<<dim3(8, 16, 9), blk, 0, stream>>>(
        q, keys, x, Wsw, bsw, s, gate);

    // 3) two-stage top-32 + softmax
    topk_kernel<<<dim3(NROWS * HEADS), dim3(64), 0, stream>>>(s, wsc, idxb);

    // 4) out0 = (sum_k w*values[idx]) * gate
    gather_kernel<<<dim3(NROWS), blk, 0, stream>>>(values, wsc, idxb, gate, out0);

    // 5) out = out0 @ Wv^T + bv
    gemm_nt<<<dim3(8, 32), blk, 0, stream>>>(
        out0, DOUT, Wv, DOUT, out, DOUT, bv, DOUT);
}